// Round 3
// baseline (12769.734 us; speedup 1.0000x reference)
//
#include <hip/hip_runtime.h>

#define USER_NUM 100000
#define ITEM_NUM 50000
#define N_NODES  150000   // USER_NUM + ITEM_NUM
#define EMB      64
#define NNZ      5000000
#define NELEM    (N_NODES * EMB)      // 9,600,000
#define NELEM4   (NELEM / 4)          // 2,400,000

// A = concat(user,item); acc(=d_out) = same; B = 0
__global__ void init_kernel(const float* __restrict__ user,
                            const float* __restrict__ item,
                            float* __restrict__ A,
                            float* __restrict__ acc,
                            float* __restrict__ B) {
    int i = blockIdx.x * blockDim.x + threadIdx.x;
    if (i >= NELEM4) return;
    int base = i * 4;                 // USER_NUM*EMB = 6.4M is 4-divisible, no straddle
    const float* src = (base < USER_NUM * EMB) ? (user + base)
                                               : (item + (base - USER_NUM * EMB));
    float4 f = *(const float4*)src;
    *(float4*)(A + base)   = f;
    *(float4*)(acc + base) = f;
    *(float4*)(B + base)   = make_float4(0.f, 0.f, 0.f, 0.f);
}

// y[row[e]] += vals[e] * x[col[e]]  — 16 threads per edge, float4 per thread
__global__ void spmm_kernel(const int* __restrict__ row,
                            const int* __restrict__ col,
                            const float* __restrict__ vals,
                            const float* __restrict__ x,
                            float* __restrict__ y) {
    int t = blockIdx.x * blockDim.x + threadIdx.x;  // up to 80M, fits int32
    int e = t >> 4;
    if (e >= NNZ) return;
    int q = (t & 15) << 2;                    // dim offset 0..60
    int dst = row[e];
    int src = col[e];
    float v = vals[e];
    float4 xv = *(const float4*)(x + src * EMB + q);
    float* yp = y + dst * EMB + q;
    unsafeAtomicAdd(yp + 0, v * xv.x);
    unsafeAtomicAdd(yp + 1, v * xv.y);
    unsafeAtomicAdd(yp + 2, v * xv.z);
    unsafeAtomicAdd(yp + 3, v * xv.w);
}

// acc += nxt; oldbuf = 0 (old ping-pong buffer becomes next layer's dst)
__global__ void add_zero_kernel(float* __restrict__ acc,
                                const float* __restrict__ nxt,
                                float* __restrict__ oldbuf) {
    int i = blockIdx.x * blockDim.x + threadIdx.x;
    if (i >= NELEM4) return;
    int base = i * 4;
    float4 a = *(const float4*)(acc + base);
    float4 n = *(const float4*)(nxt + base);
    a.x += n.x; a.y += n.y; a.z += n.z; a.w += n.w;
    *(float4*)(acc + base)    = a;
    *(float4*)(oldbuf + base) = make_float4(0.f, 0.f, 0.f, 0.f);
}

// out(=acc) = (acc + nxt) * 0.25, in place
__global__ void final_kernel(float* __restrict__ acc,
                             const float* __restrict__ nxt) {
    int i = blockIdx.x * blockDim.x + threadIdx.x;
    if (i >= NELEM4) return;
    int base = i * 4;
    float4 a = *(const float4*)(acc + base);
    float4 n = *(const float4*)(nxt + base);
    a.x = (a.x + n.x) * 0.25f;
    a.y = (a.y + n.y) * 0.25f;
    a.z = (a.z + n.z) * 0.25f;
    a.w = (a.w + n.w) * 0.25f;
    *(float4*)(acc + base) = a;
}

extern "C" void kernel_launch(void* const* d_in, const int* in_sizes, int n_in,
                              void* d_out, int out_size, void* d_ws, size_t ws_size,
                              hipStream_t stream) {
    const float* user = (const float*)d_in[0];
    const float* item = (const float*)d_in[1];
    const int*   row  = (const int*)d_in[2];
    const int*   col  = (const int*)d_in[3];
    const float* vals = (const float*)d_in[4];
    // n_layers is fixed at 3 per the reference setup (d_in[5], device scalar)

    float* A   = (float*)d_ws;
    float* B   = A + NELEM;
    float* acc = (float*)d_out;        // f32 output doubles as the accumulator

    const int eb = 256;
    const int nblk  = NELEM4 / eb;            // 9375 exact
    const int eblk  = (NNZ * 16) / eb;        // 312500 exact

    init_kernel<<<nblk, eb, 0, stream>>>(user, item, A, acc, B);

    // layer 1: A -> B
    spmm_kernel<<<eblk, eb, 0, stream>>>(row, col, vals, A, B);
    add_zero_kernel<<<nblk, eb, 0, stream>>>(acc, B, A);   // zeros A

    // layer 2: B -> A
    spmm_kernel<<<eblk, eb, 0, stream>>>(row, col, vals, B, A);
    add_zero_kernel<<<nblk, eb, 0, stream>>>(acc, A, B);   // zeros B

    // layer 3: A -> B, fused finalize (in place on d_out)
    spmm_kernel<<<eblk, eb, 0, stream>>>(row, col, vals, A, B);
    final_kernel<<<nblk, eb, 0, stream>>>(acc, B);
}

// Round 4
// 1201.945 us; speedup vs baseline: 10.6242x; 10.6242x over previous
//
#include <hip/hip_runtime.h>

#define USER_NUM 100000
#define ITEM_NUM 50000
#define N_NODES  150000
#define EMB      64
#define NNZ      5000000
#define NELEM    (N_NODES * EMB)      // 9,600,000
#define NPART    ((N_NODES + 255) / 256)   // 586

// ---------- phase 1: bucket edges by destination row ----------

__global__ void count_kernel(const int* __restrict__ row, int* __restrict__ rowcnt) {
    int e = blockIdx.x * blockDim.x + threadIdx.x;
    if (e >= NNZ) return;
    atomicAdd(&rowcnt[row[e]], 1);
}

// part[b] = sum of rowcnt chunk b
__global__ void scan_blocks(const int* __restrict__ rowcnt, int* __restrict__ part) {
    __shared__ int sdata[256];
    int i = blockIdx.x * 256 + threadIdx.x;
    sdata[threadIdx.x] = (i < N_NODES) ? rowcnt[i] : 0;
    __syncthreads();
    for (int ofs = 128; ofs > 0; ofs >>= 1) {
        if (threadIdx.x < ofs) sdata[threadIdx.x] += sdata[threadIdx.x + ofs];
        __syncthreads();
    }
    if (threadIdx.x == 0) part[blockIdx.x] = sdata[0];
}

// in-place exclusive scan of part[0..NPART) — single block, LDS staging
__global__ void scan_partials(int* __restrict__ part) {
    __shared__ int sdata[NPART];
    int t = threadIdx.x;
    for (int i = t; i < NPART; i += blockDim.x) sdata[i] = part[i];
    __syncthreads();
    if (t == 0) {
        int run = 0;
        for (int b = 0; b < NPART; ++b) { int x = sdata[b]; sdata[b] = run; run += x; }
    }
    __syncthreads();
    for (int i = t; i < NPART; i += blockDim.x) part[i] = sdata[i];
}

// rowoff[i] = exclusive scan of rowcnt (global)
__global__ void scan_final(const int* __restrict__ rowcnt, const int* __restrict__ part,
                           int* __restrict__ rowoff) {
    __shared__ int sdata[256];
    int i = blockIdx.x * 256 + threadIdx.x;
    int vcur = (i < N_NODES) ? rowcnt[i] : 0;
    sdata[threadIdx.x] = vcur;
    __syncthreads();
    // Hillis-Steele inclusive scan (read-sync-write-sync per step)
    for (int ofs = 1; ofs < 256; ofs <<= 1) {
        int t = (threadIdx.x >= ofs) ? sdata[threadIdx.x - ofs] : 0;
        __syncthreads();
        sdata[threadIdx.x] += t;
        __syncthreads();
    }
    if (i < N_NODES) rowoff[i] = part[blockIdx.x] + sdata[threadIdx.x] - vcur;
}

// scatter edges into row-sorted order; mutates rowoff so that afterwards
// rowoff[r] == end-of-row-r (exclusive-scan property)
__global__ void scatter_kernel(const int* __restrict__ row, const int* __restrict__ col,
                               const float* __restrict__ vals,
                               int* __restrict__ rowoff,
                               int* __restrict__ scol, float* __restrict__ sval) {
    int e = blockIdx.x * blockDim.x + threadIdx.x;
    if (e >= NNZ) return;
    int r = row[e];
    int pos = atomicAdd(&rowoff[r], 1);
    scol[pos] = col[e];
    sval[pos] = vals[e];
}

// ---------- phase 2: one wave per destination row ----------

template <int MODE>
__device__ __forceinline__ float gatherx(const float* __restrict__ x,
                                         const float* __restrict__ user,
                                         const float* __restrict__ item,
                                         int c, int lane) {
    if (MODE == 1) {
        const float* p = (c < USER_NUM) ? (user + c * EMB) : (item + (c - USER_NUM) * EMB);
        return p[lane];
    } else {
        return x[c * EMB + lane];
    }
}

// MODE 1: x = virtual concat(user,item); ynext = s; acc = ego0 + s
// MODE 2: x = prev buf;                  ynext = s; acc += s
// MODE 3: x = prev buf;                  acc = (acc + s) * 0.25
template <int MODE>
__global__ __launch_bounds__(256) void spmm_row_kernel(
        const int* __restrict__ rowend,
        const int* __restrict__ scol, const float* __restrict__ sval,
        const float* __restrict__ x,
        const float* __restrict__ user, const float* __restrict__ item,
        float* __restrict__ ynext, float* __restrict__ acc) {
    int wave = threadIdx.x >> 6;
    int lane = threadIdx.x & 63;
    int r = blockIdx.x * 4 + wave;
    if (r >= N_NODES) return;
    int start = (r == 0) ? 0 : rowend[r - 1];
    int end = rowend[r];
    float s = 0.f;
    for (int base = start; base < end; base += 64) {
        int n = end - base; if (n > 64) n = 64;
        int c = 0; float v = 0.f;
        if (lane < n) { c = scol[base + lane]; v = sval[base + lane]; }
        int j = 0;
        for (; j + 4 <= n; j += 4) {
            int   c0 = __shfl(c, j),     c1 = __shfl(c, j + 1);
            int   c2 = __shfl(c, j + 2), c3 = __shfl(c, j + 3);
            float v0 = __shfl(v, j),     v1 = __shfl(v, j + 1);
            float v2 = __shfl(v, j + 2), v3 = __shfl(v, j + 3);
            float x0 = gatherx<MODE>(x, user, item, c0, lane);
            float x1 = gatherx<MODE>(x, user, item, c1, lane);
            float x2 = gatherx<MODE>(x, user, item, c2, lane);
            float x3 = gatherx<MODE>(x, user, item, c3, lane);
            s += v0 * x0; s += v1 * x1; s += v2 * x2; s += v3 * x3;
        }
        for (; j < n; ++j) {
            int cj = __shfl(c, j);
            float vj = __shfl(v, j);
            s += vj * gatherx<MODE>(x, user, item, cj, lane);
        }
    }
    int o = r * EMB + lane;
    if (MODE == 1) {
        float e0 = (r < USER_NUM) ? user[o] : item[o - USER_NUM * EMB];
        ynext[o] = s;
        acc[o] = e0 + s;
    } else if (MODE == 2) {
        ynext[o] = s;
        acc[o] += s;
    } else {
        acc[o] = (acc[o] + s) * 0.25f;
    }
}

extern "C" void kernel_launch(void* const* d_in, const int* in_sizes, int n_in,
                              void* d_out, int out_size, void* d_ws, size_t ws_size,
                              hipStream_t stream) {
    const float* user = (const float*)d_in[0];
    const float* item = (const float*)d_in[1];
    const int*   row  = (const int*)d_in[2];
    const int*   col  = (const int*)d_in[3];
    const float* vals = (const float*)d_in[4];

    float* A      = (float*)d_ws;            // 38.4 MB
    float* B      = A + NELEM;               // 38.4 MB
    int*   scol   = (int*)(B + NELEM);       // 20 MB
    float* sval   = (float*)(scol + NNZ);    // 20 MB
    int*   rowcnt = (int*)(sval + NNZ);      // 0.6 MB
    int*   rowoff = rowcnt + N_NODES;        // 0.6 MB
    int*   part   = rowoff + N_NODES;        // ~2.4 KB
    float* acc    = (float*)d_out;

    const int eb = 256;
    const int egrid = (NNZ + eb - 1) / eb;        // 19532
    const int rgrid = N_NODES / 4;                // 37500

    hipMemsetAsync(rowcnt, 0, N_NODES * sizeof(int), stream);
    count_kernel<<<egrid, eb, 0, stream>>>(row, rowcnt);
    scan_blocks<<<NPART, 256, 0, stream>>>(rowcnt, part);
    scan_partials<<<1, 1024, 0, stream>>>(part);
    scan_final<<<NPART, 256, 0, stream>>>(rowcnt, part, rowoff);
    scatter_kernel<<<egrid, eb, 0, stream>>>(row, col, vals, rowoff, scol, sval);
    // rowoff[r] is now end-of-row-r

    // layer 1: concat(user,item) -> B ; acc = ego0 + B
    spmm_row_kernel<1><<<rgrid, eb, 0, stream>>>(rowoff, scol, sval, nullptr, user, item, B, acc);
    // layer 2: B -> A ; acc += A
    spmm_row_kernel<2><<<rgrid, eb, 0, stream>>>(rowoff, scol, sval, B, user, item, A, acc);
    // layer 3: A -> (fused) ; acc = (acc + y) * 0.25
    spmm_row_kernel<3><<<rgrid, eb, 0, stream>>>(rowoff, scol, sval, A, user, item, nullptr, acc);
}